// Round 3
// baseline (9445.781 us; speedup 1.0000x reference)
//
#include <hip/hip_runtime.h>

// ---------------------------------------------------------------------------
// Seq2Seq LSTM (B=16, H=256, L=2, S=128, T=128, V=32000).
// Inputs fp32 (per reference dtypes), output fp32. Internal compute: bf16 MFMA
// with fp32 accumulation; h and Whh use hi/lo bf16 splits for fp32-class
// accuracy in the recurrence.
// Pipeline:
//   whh_split x4 -> gathers -> [GEMM P=X@Wih^T+b -> lstm_recur] x4
//   -> attn projections -> fused score/softmax/ctx -> logits GEMM + zero_t0.
// Bulk scratch lives inside d_out (fully overwritten at the end);
// d_ws holds only Acat + flags + cfin (~2.1 MB).
// Cross-block recurrence sync: agent-scope atomics (coherent across XCDs).
// ---------------------------------------------------------------------------

typedef __attribute__((ext_vector_type(8))) short s8v;
typedef __attribute__((ext_vector_type(8))) __bf16 bf8v;
typedef __attribute__((ext_vector_type(4))) float f4v;

#define HDIM 256
#define DLEN 127
#define NVOC 32000

__device__ __forceinline__ float bf2f(unsigned short u) {
  union { unsigned int i; float f; } v; v.i = ((unsigned int)u) << 16; return v.f;
}
__device__ __forceinline__ unsigned short f2bf(float x) {
  union { float f; unsigned int i; } v; v.f = x;
  unsigned int u = v.i;
  return (unsigned short)((u + 0x7FFFu + ((u >> 16) & 1u)) >> 16);
}
__device__ __forceinline__ float sigm(float x) {
  x = fminf(fmaxf(x, -30.f), 30.f);
  return 1.f / (1.f + __expf(-x));
}
__device__ __forceinline__ float tanh_f(float x) {
  float y = fminf(fmaxf(x, -15.f), 15.f);
  float e = __expf(2.f * y);
  return (e - 1.f) / (e + 1.f);
}
__device__ __forceinline__ f4v mfma_bf16(s8v a, s8v b, f4v c) {
  return __builtin_amdgcn_mfma_f32_16x16x32_bf16(
      __builtin_bit_cast(bf8v, a), __builtin_bit_cast(bf8v, b), c, 0, 0, 0);
}

// ---------------- split fp32 weight matrix into bf16 hi + lo ----------------
__global__ __launch_bounds__(256) void whh_split(
    const float* __restrict__ W, unsigned short* __restrict__ Hh,
    unsigned short* __restrict__ Hl) {
  int i = blockIdx.x * 256 + threadIdx.x;      // grid 1024 -> 262144
  float w = W[i];
  unsigned short h = f2bf(w);
  Hh[i] = h;
  Hl[i] = f2bf(w - bf2f(h));
}

// ---------------- embedding gather: fp32 emb -> bf16 rows ----------------
__global__ __launch_bounds__(64) void gather_rows(
    const int* __restrict__ toks, const float* __restrict__ emb,
    unsigned short* __restrict__ out, int dec) {
  int r = blockIdx.x, tid = threadIdx.x;
  int token = dec ? toks[(r / DLEN) * 128 + (r % DLEN)] : toks[r];
  float4 v = *(const float4*)&emb[(long)token * HDIM + tid * 4];
  unsigned short q[4] = {f2bf(v.x), f2bf(v.y), f2bf(v.z), f2bf(v.w)};
  *(uint2*)&out[(long)r * HDIM + tid * 4] = *(uint2*)q;
}

// ---------------- zero first timestep of output (fp32) ----------------
__global__ __launch_bounds__(256) void zero_t0(float* __restrict__ out) {
  int i = blockIdx.x * 256 + threadIdx.x;      // grid 500 -> 128000
  int b = i / 8000, off = (i - b * 8000) * 4;
  float4 z = {0.f, 0.f, 0.f, 0.f};
  *(float4*)&out[(long)b * 128 * NVOC + off] = z;
}

// ---------------- GEMM: C = A(MxK,bf16) @ B(NxK,fp32)^T + bias ----------------
// mode 0: fp32 out Cf (ldc). mode 1: fp32 out, row m -> row (m/Tl)*128+(m%Tl)+1.
// Loops miters m-tiles per block: m0 = (blockIdx.y*miters + mi)*128.
__global__ __launch_bounds__(256) void gemm_bt(
    const unsigned short* __restrict__ A, int lda,
    const float* __restrict__ B, int ldb,
    int M, int K,
    const float* __restrict__ bias1, const float* __restrict__ bias2,
    float* __restrict__ Cf, int ldc, int mode, int Tl, int miters) {
  __shared__ unsigned short As[128 * 40];
  __shared__ unsigned short Bs[128 * 40];
  int tid = threadIdx.x;
  int lane = tid & 63, wid = tid >> 6;
  int wm = (wid >> 1) * 64, wn = (wid & 1) * 64;
  int r16 = lane & 15, kg = lane >> 4;
  int n0 = blockIdx.x * 128;

  for (int mi = 0; mi < miters; mi++) {
    int m0 = (blockIdx.y * miters + mi) * 128;
    f4v acc[4][4];
    for (int i = 0; i < 4; i++)
      for (int j = 0; j < 4; j++) acc[i][j] = (f4v){0.f, 0.f, 0.f, 0.f};

    for (int k0 = 0; k0 < K; k0 += 32) {
      for (int i = 0; i < 2; i++) {
        int idx = tid + i * 256;
        int row = idx >> 2, kc = (idx & 3) * 8;
        uint4 va = {0u, 0u, 0u, 0u};
        int gm = m0 + row;
        if (gm < M) va = *(const uint4*)&A[(long)gm * lda + k0 + kc];
        *(uint4*)&As[row * 40 + kc] = va;
        const float* bp = &B[(long)(n0 + row) * ldb + k0 + kc];
        float4 b0 = *(const float4*)bp, b1 = *(const float4*)(bp + 4);
        unsigned short q[8] = {f2bf(b0.x), f2bf(b0.y), f2bf(b0.z), f2bf(b0.w),
                               f2bf(b1.x), f2bf(b1.y), f2bf(b1.z), f2bf(b1.w)};
        *(uint4*)&Bs[row * 40 + kc] = *(uint4*)q;
      }
      __syncthreads();
      s8v af[4], bfg[4];
      for (int f = 0; f < 4; f++) {
        af[f]  = *(const s8v*)&As[(wm + f * 16 + r16) * 40 + kg * 8];
        bfg[f] = *(const s8v*)&Bs[(wn + f * 16 + r16) * 40 + kg * 8];
      }
      for (int i = 0; i < 4; i++)
        for (int j = 0; j < 4; j++)
          acc[i][j] = mfma_bf16(af[i], bfg[j], acc[i][j]);
      __syncthreads();
    }

    int rbase = (lane >> 4) * 4;
    for (int j = 0; j < 4; j++) {
      int n = n0 + wn + j * 16 + r16;
      float bv = 0.f;
      if (bias1) bv += bias1[n];
      if (bias2) bv += bias2[n];
      for (int i = 0; i < 4; i++) {
        for (int r = 0; r < 4; r++) {
          int m = m0 + wm + i * 16 + rbase + r;
          if (m < M) {
            float v = acc[i][j][r] + bv;
            if (mode == 0) {
              Cf[(long)m * ldc + n] = v;
            } else {
              int bb = m / Tl, tt = m - bb * Tl;
              Cf[(long)(bb * 128 + tt + 1) * ldc + n] = v;
            }
          }
        }
      }
    }
    __syncthreads();
  }
}

// ---------------- LSTM recurrence ----------------
// grid 121; workers at blockIdx%8==0 (16). Worker blk owns units [blk*16,+16).
// Wave g computes gate g for 16 units x 16 batches via MFMA; Whh hi/lo
// fragments persistent in VGPRs (3-term product with h hi/lo split).
__global__ __launch_bounds__(256) void lstm_recur(
    const float* __restrict__ P,              // [16*Tl][1024], rows b*Tl+t
    const unsigned short* __restrict__ WhhH,  // [1024][256] bf16 hi
    const unsigned short* __restrict__ WhhL,  // [1024][256] bf16 lo
    float* __restrict__ hsync,                // [Tl][16][256]
    int* __restrict__ arr,                    // [Tl] arrival counters (zeroed)
    const float* __restrict__ hinit,          // [16][256] or null
    const float* __restrict__ cinit,          // [16][256] or null
    unsigned short* __restrict__ hout, int ldo, int coloff,
    float* __restrict__ cfin, int Tl) {
  int widx = (int)blockIdx.x;
  if (widx & 7) return;
  int blk = widx >> 3;                        // 0..15
  __shared__ unsigned short hh[16 * 264];
  __shared__ unsigned short hl[16 * 264];
  __shared__ float gbuf[4][16][16];
  int tid = threadIdx.x;
  int lane = tid & 63, gate = tid >> 6;
  int U = blk * 16;
  int r16 = lane & 15, kg = lane >> 4;

  s8v wfh[8], wfl[8];
  {
    long roff = (long)(gate * 256 + U + r16) * 256 + kg * 8;
    for (int kt = 0; kt < 8; kt++) {
      wfh[kt] = *(const s8v*)(WhhH + roff + kt * 32);
      wfl[kt] = *(const s8v*)(WhhL + roff + kt * 32);
    }
  }
  int b = tid >> 4, u = tid & 15;
  float c = cinit ? cinit[b * 256 + U + u] : 0.f;

  for (int t = 0; t < Tl; t++) {
    if (t > 0) {
      if (tid == 0) {
        while (__hip_atomic_load(arr + (t - 1), __ATOMIC_ACQUIRE,
                                 __HIP_MEMORY_SCOPE_AGENT) < 16) {}
      }
      __syncthreads();
      const float* hp = hsync + (size_t)(t - 1) * 4096;
      for (int i = 0; i < 16; i++) {
        float v = __hip_atomic_load(hp + i * 256 + tid, __ATOMIC_RELAXED,
                                    __HIP_MEMORY_SCOPE_AGENT);
        unsigned short hb = f2bf(v);
        hh[i * 264 + tid] = hb;
        hl[i * 264 + tid] = f2bf(v - bf2f(hb));
      }
    } else {
      for (int i = 0; i < 16; i++) {
        float v = hinit ? hinit[i * 256 + tid] : 0.f;
        unsigned short hb = f2bf(v);
        hh[i * 264 + tid] = hb;
        hl[i * 264 + tid] = f2bf(v - bf2f(hb));
      }
    }
    const float* prow = P + (size_t)(b * Tl + t) * 1024 + U + u;
    float p0 = prow[0], p1 = prow[256], p2 = prow[512], p3 = prow[768];
    __syncthreads();
    f4v acc = (f4v){0.f, 0.f, 0.f, 0.f};
    for (int kt = 0; kt < 8; kt++) {
      s8v ah = *(const s8v*)&hh[r16 * 264 + kt * 32 + kg * 8];
      s8v al = *(const s8v*)&hl[r16 * 264 + kt * 32 + kg * 8];
      acc = mfma_bf16(ah, wfh[kt], acc);
      acc = mfma_bf16(al, wfh[kt], acc);
      acc = mfma_bf16(ah, wfl[kt], acc);
    }
    for (int r = 0; r < 4; r++) gbuf[gate][kg * 4 + r][r16] = acc[r];
    __syncthreads();
    float gi = gbuf[0][b][u] + p0;
    float gf = gbuf[1][b][u] + p1;
    float gg = gbuf[2][b][u] + p2;
    float go = gbuf[3][b][u] + p3;
    c = sigm(gf) * c + sigm(gi) * tanh_f(gg);
    float h = sigm(go) * tanh_f(c);
    __hip_atomic_store(hsync + (size_t)t * 4096 + b * 256 + U + u, h,
                       __ATOMIC_RELAXED, __HIP_MEMORY_SCOPE_AGENT);
    hout[(size_t)(b * Tl + t) * ldo + coloff + U + u] = f2bf(h);
    __threadfence();
    __syncthreads();
    if (tid == 0)
      __hip_atomic_fetch_add(arr + t, 1, __ATOMIC_RELEASE, __HIP_MEMORY_SCOPE_AGENT);
  }
  if (cfin) cfin[b * 256 + U + u] = c;
}

// ---------------- attention: scores + softmax + context ----------------
__global__ __launch_bounds__(256) void attn_ctx(
    const float* __restrict__ dp,       // [2032][256] (includes attn_b)
    const float* __restrict__ ep,       // [2048][256]
    const float* __restrict__ vw,       // [256]
    const float* __restrict__ enc_out,  // [128][16][256] fp32 (hs1)
    unsigned short* __restrict__ Acat)  // [2032][512], write cols 256..511
{
  __shared__ float sdp[256], sv[256], sc[128];
  int bt = blockIdx.x;
  int b = bt / DLEN;
  int tid = threadIdx.x;
  sdp[tid] = dp[(long)bt * 256 + tid];
  sv[tid] = vw[tid];
  __syncthreads();
  int lane = tid & 63, wid = tid >> 6;
  for (int i = 0; i < 32; i++) {
    int s = wid * 32 + i;
    float4 e4 = *(const float4*)&ep[(long)(b * 128 + s) * 256 + lane * 4];
    int h0 = lane * 4;
    float part = sv[h0] * tanh_f(sdp[h0] + e4.x);
    part += sv[h0 + 1] * tanh_f(sdp[h0 + 1] + e4.y);
    part += sv[h0 + 2] * tanh_f(sdp[h0 + 2] + e4.z);
    part += sv[h0 + 3] * tanh_f(sdp[h0 + 3] + e4.w);
    for (int off = 32; off >= 1; off >>= 1) part += __shfl_xor(part, off);
    if (lane == 0) sc[s] = part;
  }
  __syncthreads();
  if (wid == 0) {
    float a0 = sc[lane], a1 = sc[lane + 64];
    float mx = fmaxf(a0, a1);
    for (int off = 32; off >= 1; off >>= 1) mx = fmaxf(mx, __shfl_xor(mx, off));
    float e0 = __expf(a0 - mx), e1 = __expf(a1 - mx);
    float sm = e0 + e1;
    for (int off = 32; off >= 1; off >>= 1) sm += __shfl_xor(sm, off);
    float inv = 1.0f / sm;
    sc[lane] = e0 * inv;
    sc[lane + 64] = e1 * inv;
  }
  __syncthreads();
  float acc = 0.f;
  for (int s = 0; s < 128; s++)
    acc += sc[s] * enc_out[(long)(s * 16 + b) * 256 + tid];
  Acat[(long)bt * 512 + 256 + tid] = f2bf(acc);
}

// ---------------------------------------------------------------------------
extern "C" void kernel_launch(void* const* d_in, const int* in_sizes, int n_in,
                              void* d_out, int out_size, void* d_ws, size_t ws_size,
                              hipStream_t stream) {
  (void)in_sizes; (void)n_in; (void)out_size; (void)ws_size;
  const int* src = (const int*)d_in[0];
  const int* tgt = (const int*)d_in[1];
  auto F32 = [&](int i) { return (const float*)d_in[i]; };
  const float* enc_emb = F32(2);
  const float* dec_emb = F32(3);
  // enc l0: 4..7 (Wih,Whh,bih,bhh), enc l1: 8..11, dec l0: 12..15, dec l1: 16..19
  const float* attnW = F32(20);
  const float* attnB = F32(21);
  const float* vw = F32(22);
  const float* outW = F32(23);
  const float* outB = F32(24);
  float* out = (float*)d_out;

  // ---- bulk scratch inside d_out (dead before final logits/zero writes) ----
  float* Pf  = out;                        // 2,097,152 f
  float* hs0 = Pf + 2097152;               // 524,288 f each
  float* hs1 = hs0 + 524288;
  float* hs2 = hs1 + 524288;
  float* hs3 = hs2 + 524288;
  float* dpf = hs3 + 524288;               // 524,288 f (uses 520,192)
  float* epf = dpf + 524288;               // 524,288 f
  unsigned short* WHB = (unsigned short*)(epf + 524288);  // 8 x 262,144 shorts
  unsigned short* WhhH[4], *WhhL[4];
  for (int l = 0; l < 4; l++) {
    WhhH[l] = WHB + (size_t)l * 524288;
    WhhL[l] = WHB + (size_t)l * 524288 + 262144;
  }
  unsigned short* XB = WHB + (size_t)4 * 524288;          // 5 x 524,288 shorts
  unsigned short* Xe  = XB;
  unsigned short* X2  = XB + 524288;
  unsigned short* Xd  = XB + 2 * 524288;
  unsigned short* Xd2 = XB + 3 * 524288;
  unsigned short* Ebf = XB + 4 * 524288;
  // total: ~7.6M floats = 30.4 MB << 65.5M floats of d_out

  // ---- minimal d_ws usage (live during logits GEMM) ----
  char* w = (char*)d_ws;
  unsigned short* Acat = (unsigned short*)w;              // 2,080,768 B
  int* arrAll = (int*)(w + 2097152);                      // 4*128*4 B
  float* cfin = (float*)(w + 2097152 + 4096);             // 2*4096*4 B
  int* arr0 = arrAll, *arr1 = arrAll + 128, *arr2 = arrAll + 256,
     * arr3 = arrAll + 384;
  float* cfin0 = cfin, *cfin1 = cfin + 4096;

  hipMemsetAsync(arrAll, 0, 4096, stream);
  // weight hi/lo splits (Whh of the 4 layer-runs: in[5],[9],[13],[17])
  whh_split<<<1024, 256, 0, stream>>>(F32(5),  WhhH[0], WhhL[0]);
  whh_split<<<1024, 256, 0, stream>>>(F32(9),  WhhH[1], WhhL[1]);
  whh_split<<<1024, 256, 0, stream>>>(F32(13), WhhH[2], WhhL[2]);
  whh_split<<<1024, 256, 0, stream>>>(F32(17), WhhH[3], WhhL[3]);
  gather_rows<<<2048, 64, 0, stream>>>(src, enc_emb, Xe, 0);
  gather_rows<<<2032, 64, 0, stream>>>(tgt, dec_emb, Xd, 1);
  // encoder layer 0
  gemm_bt<<<dim3(8, 16), 256, 0, stream>>>(Xe, 256, F32(4), 256, 2048, 256,
      F32(6), F32(7), Pf, 1024, 0, 0, 1);
  lstm_recur<<<121, 256, 0, stream>>>(Pf, WhhH[0], WhhL[0], hs0, arr0,
      nullptr, nullptr, X2, 256, 0, cfin0, 128);
  // encoder layer 1
  gemm_bt<<<dim3(8, 16), 256, 0, stream>>>(X2, 256, F32(8), 256, 2048, 256,
      F32(10), F32(11), Pf, 1024, 0, 0, 1);
  lstm_recur<<<121, 256, 0, stream>>>(Pf, WhhH[1], WhhL[1], hs1, arr1,
      nullptr, nullptr, Ebf, 256, 0, cfin1, 128);
  // decoder layer 0 (init = enc layer0 finals)
  gemm_bt<<<dim3(8, 16), 256, 0, stream>>>(Xd, 256, F32(12), 256, 2032, 256,
      F32(14), F32(15), Pf, 1024, 0, 0, 1);
  lstm_recur<<<121, 256, 0, stream>>>(Pf, WhhH[2], WhhL[2], hs2, arr2,
      hs0 + (size_t)127 * 4096, cfin0, Xd2, 256, 0, nullptr, 127);
  // decoder layer 1 (init = enc layer1 finals); h -> Acat cols 0..255
  gemm_bt<<<dim3(8, 16), 256, 0, stream>>>(Xd2, 256, F32(16), 256, 2032, 256,
      F32(18), F32(19), Pf, 1024, 0, 0, 1);
  lstm_recur<<<121, 256, 0, stream>>>(Pf, WhhH[3], WhhL[3], hs3, arr3,
      hs1 + (size_t)127 * 4096, cfin1, Acat, 512, 0, nullptr, 127);
  // attention projections: dp = dec_out@Wd^T + attn_b ; ep = enc_out@We^T
  gemm_bt<<<dim3(2, 16), 256, 0, stream>>>(Acat, 512, attnW, 512, 2032, 256,
      attnB, nullptr, dpf, 256, 0, 0, 1);
  gemm_bt<<<dim3(2, 16), 256, 0, stream>>>(Ebf, 256, attnW + 256, 512, 2048, 256,
      nullptr, nullptr, epf, 256, 0, 0, 1);
  attn_ctx<<<2032, 256, 0, stream>>>(dpf, epf, vw, hs1, Acat);
  // ---- final writes: every element of d_out is overwritten from here ----
  gemm_bt<<<dim3(250, 4), 256, 0, stream>>>(Acat, 512, outW, 512, 2032, 512,
      outB, nullptr, out, NVOC, 1, 127, 4);
  zero_t0<<<500, 256, 0, stream>>>(out);
}